// Round 2
// baseline (979.664 us; speedup 1.0000x reference)
//
#include <hip/hip_runtime.h>
#include <math.h>

#define NB 16
#define NS 1024
#define ND 768
#define NH 12
#define NDH 64

static constexpr size_t QKV_ELEMS = (size_t)NB * NH * NS * NDH;  // 12.58M floats

// ---------------------------------------------------------------------------
// Kernel 1: per-head QKV projection.
//   x: [B*S, 768] fp32. W*: [H, 64, 64] (out,in). b*: [H, 64].
//   Outputs q,k,v in [B, H, S, 64] layout. q pre-scaled by 1/sqrt(64).
// grid: (B*S/64, H), block 256. W rows live in registers (d-chunked).
// ---------------------------------------------------------------------------
__global__ __launch_bounds__(256) void qkv_proj_kernel(
    const float* __restrict__ x,
    const float* __restrict__ Wq, const float* __restrict__ bq,
    const float* __restrict__ Wk, const float* __restrict__ bk,
    const float* __restrict__ Wv, const float* __restrict__ bv,
    float* __restrict__ qo, float* __restrict__ ko, float* __restrict__ vo)
{
    __shared__ float xs[64][68];            // 64 tokens x 64 dims (padded)
    const int tb = blockIdx.x;              // token tile (64 tokens)
    const int h  = blockIdx.y;
    const int t  = threadIdx.x;
    const int e  = t & 63;                  // output dim
    const int tg = t >> 6;                  // wave id 0..3
    const long tok0 = (long)tb * 64;        // flattened token base (b*S+s)

    // stage x tile (head-h slice), float4 coalesced
    #pragma unroll
    for (int r = 0; r < 4; ++r) {
        const int vi  = r * 256 + t;
        const int row = vi >> 4;
        const int c4  = (vi & 15) << 2;
        const float4 val = *reinterpret_cast<const float4*>(
            &x[(tok0 + row) * ND + h * NDH + c4]);
        *reinterpret_cast<float4*>(&xs[row][c4]) = val;
    }
    __syncthreads();

    float acc[3][16];
    #pragma unroll
    for (int m = 0; m < 3; ++m)
        #pragma unroll
        for (int p = 0; p < 16; ++p) acc[m][p] = 0.f;

    // d-chunked: 16 W coefficients per matrix in registers at a time
    #pragma unroll
    for (int dc = 0; dc < 4; ++dc) {
        float wr0[16], wr1[16], wr2[16];
        #pragma unroll
        for (int i4 = 0; i4 < 4; ++i4) {
            const size_t wbase = (size_t)(h * NDH + e) * NDH + dc * 16 + i4 * 4;
            const float4 a = *reinterpret_cast<const float4*>(&Wq[wbase]);
            const float4 b = *reinterpret_cast<const float4*>(&Wk[wbase]);
            const float4 c = *reinterpret_cast<const float4*>(&Wv[wbase]);
            wr0[i4*4+0]=a.x; wr0[i4*4+1]=a.y; wr0[i4*4+2]=a.z; wr0[i4*4+3]=a.w;
            wr1[i4*4+0]=b.x; wr1[i4*4+1]=b.y; wr1[i4*4+2]=b.z; wr1[i4*4+3]=b.w;
            wr2[i4*4+0]=c.x; wr2[i4*4+1]=c.y; wr2[i4*4+2]=c.z; wr2[i4*4+3]=c.w;
        }
        #pragma unroll
        for (int p = 0; p < 16; ++p) {
            const int token = p * 4 + tg;   // whole wave shares one token -> LDS broadcast
            #pragma unroll
            for (int i = 0; i < 16; ++i) {
                const float xd = xs[token][dc * 16 + i];
                acc[0][p] = fmaf(xd, wr0[i], acc[0][p]);
                acc[1][p] = fmaf(xd, wr1[i], acc[1][p]);
                acc[2][p] = fmaf(xd, wr2[i], acc[2][p]);
            }
        }
    }

    const float bqv = bq[h * NDH + e];
    const float bkv = bk[h * NDH + e];
    const float bvv = bv[h * NDH + e];
    const float scale = 0.125f;             // 1/sqrt(64) folded into q

    #pragma unroll
    for (int p = 0; p < 16; ++p) {
        const int gt = (int)tok0 + p * 4 + tg;   // b*S + s
        const int b  = gt >> 10;
        const int s  = gt & 1023;
        const size_t oidx = ((size_t)(b * NH + h) * NS + s) * NDH + e;
        qo[oidx] = (acc[0][p] + bqv) * scale;
        ko[oidx] = acc[1][p] + bkv;
        vo[oidx] = acc[2][p] + bvv;
    }
}

// ---------------------------------------------------------------------------
// Kernel 2: flash attention, fp32 vector. One block = one (b,h) x 64-row
// q-tile. 256 threads = 16x16 grid of 4x4 register tiles. Q^T/K^T/P^T in LDS
// so all inner-loop LDS reads are float4.
// ---------------------------------------------------------------------------
__global__ __launch_bounds__(256) void flash_kernel(
    const float* __restrict__ qi, const float* __restrict__ ki,
    const float* __restrict__ vi_, float* __restrict__ out)
{
    __shared__ float qT[64][68];   // [d][qr]
    __shared__ float kT[64][68];   // [d][kc]
    __shared__ float vs[64][68];   // [kc][e]
    __shared__ float pT[64][68];   // [kc][qr]

    const int bid = blockIdx.x;     // B*H*16
    const int qt  = bid & 15;
    const int bh  = bid >> 4;
    const int t   = threadIdx.x;
    const int tq  = t >> 4;         // 0..15 -> q rows 4tq..4tq+3
    const int tk  = t & 15;         // 0..15 -> k cols / out dims 4tk..4tk+3
    const size_t base = (size_t)bh * NS * NDH;

    // load Q tile transposed
    #pragma unroll
    for (int r = 0; r < 4; ++r) {
        const int vi  = r * 256 + t;
        const int row = vi >> 4;
        const int c4  = (vi & 15) << 2;
        const float4 val = *reinterpret_cast<const float4*>(
            &qi[base + (size_t)(qt * 64 + row) * NDH + c4]);
        qT[c4 + 0][row] = val.x;
        qT[c4 + 1][row] = val.y;
        qT[c4 + 2][row] = val.z;
        qT[c4 + 3][row] = val.w;
    }

    float m_i[4], l_i[4], acc[4][4];
    #pragma unroll
    for (int i = 0; i < 4; ++i) {
        m_i[i] = -INFINITY;
        l_i[i] = 0.f;
        #pragma unroll
        for (int j = 0; j < 4; ++j) acc[i][j] = 0.f;
    }
    __syncthreads();

    for (int kt_ = 0; kt_ < 16; ++kt_) {
        // stage K^T (transposed) and V (direct)
        #pragma unroll
        for (int r = 0; r < 4; ++r) {
            const int vi  = r * 256 + t;
            const int row = vi >> 4;
            const int c4  = (vi & 15) << 2;
            const size_t gidx = base + (size_t)(kt_ * 64 + row) * NDH + c4;
            const float4 kv4 = *reinterpret_cast<const float4*>(&ki[gidx]);
            kT[c4 + 0][row] = kv4.x;
            kT[c4 + 1][row] = kv4.y;
            kT[c4 + 2][row] = kv4.z;
            kT[c4 + 3][row] = kv4.w;
            const float4 vv4 = *reinterpret_cast<const float4*>(&vi_[gidx]);
            *reinterpret_cast<float4*>(&vs[row][c4]) = vv4;
        }
        __syncthreads();

        // QK^T -> s_[i][j]  (q pre-scaled)
        float s_[4][4];
        #pragma unroll
        for (int i = 0; i < 4; ++i)
            #pragma unroll
            for (int j = 0; j < 4; ++j) s_[i][j] = 0.f;

        #pragma unroll 8
        for (int d = 0; d < 64; ++d) {
            const float4 qv = *reinterpret_cast<const float4*>(&qT[d][tq * 4]);
            const float4 kv = *reinterpret_cast<const float4*>(&kT[d][tk * 4]);
            const float qa[4] = {qv.x, qv.y, qv.z, qv.w};
            const float ka[4] = {kv.x, kv.y, kv.z, kv.w};
            #pragma unroll
            for (int i = 0; i < 4; ++i)
                #pragma unroll
                for (int j = 0; j < 4; ++j)
                    s_[i][j] = fmaf(qa[i], ka[j], s_[i][j]);
        }

        // online softmax update (row stats across the 16 tk-lanes, same wave)
        float pr[4][4];
        #pragma unroll
        for (int i = 0; i < 4; ++i) {
            float rm = fmaxf(fmaxf(s_[i][0], s_[i][1]), fmaxf(s_[i][2], s_[i][3]));
            rm = fmaxf(rm, __shfl_xor(rm, 1));
            rm = fmaxf(rm, __shfl_xor(rm, 2));
            rm = fmaxf(rm, __shfl_xor(rm, 4));
            rm = fmaxf(rm, __shfl_xor(rm, 8));
            const float mn = fmaxf(m_i[i], rm);
            const float corr = __expf(m_i[i] - mn);
            m_i[i] = mn;
            float rs = 0.f;
            #pragma unroll
            for (int j = 0; j < 4; ++j) {
                pr[i][j] = __expf(s_[i][j] - mn);
                rs += pr[i][j];
            }
            rs += __shfl_xor(rs, 1);
            rs += __shfl_xor(rs, 2);
            rs += __shfl_xor(rs, 4);
            rs += __shfl_xor(rs, 8);
            l_i[i] = l_i[i] * corr + rs;
            #pragma unroll
            for (int j = 0; j < 4; ++j) acc[i][j] *= corr;
        }

        // write P^T; producer/consumer of each pT column-slice are the SAME
        // wave (wave w covers tq in {4w..4w+3} x all tk; consumer lane tq=r
        // reads cols 4r..4r+3, written only by wave w), and DS ops within a
        // wave complete in order -> no barrier needed.
        #pragma unroll
        for (int i = 0; i < 4; ++i)
            #pragma unroll
            for (int j = 0; j < 4; ++j)
                pT[tk * 4 + j][tq * 4 + i] = pr[i][j];

        // PV accumulate
        #pragma unroll 8
        for (int kc = 0; kc < 64; ++kc) {
            const float4 pv = *reinterpret_cast<const float4*>(&pT[kc][tq * 4]);
            const float4 vv = *reinterpret_cast<const float4*>(&vs[kc][tk * 4]);
            const float pa[4] = {pv.x, pv.y, pv.z, pv.w};
            const float va[4] = {vv.x, vv.y, vv.z, vv.w};
            #pragma unroll
            for (int i = 0; i < 4; ++i)
                #pragma unroll
                for (int j = 0; j < 4; ++j)
                    acc[i][j] = fmaf(pa[i], va[j], acc[i][j]);
        }
        __syncthreads();   // protect kT/vs before next stage
    }

    // epilogue: out[b, s, h*64 + e]
    const int b = bh / NH;
    const int h = bh % NH;
    #pragma unroll
    for (int i = 0; i < 4; ++i) {
        const float inv = 1.0f / l_i[i];
        const int s = qt * 64 + tq * 4 + i;
        float4 o;
        o.x = acc[i][0] * inv;
        o.y = acc[i][1] * inv;
        o.z = acc[i][2] * inv;
        o.w = acc[i][3] * inv;
        *reinterpret_cast<float4*>(
            &out[(size_t)(b * NS + s) * ND + h * NDH + tk * 4]) = o;
    }
}

// ---------------------------------------------------------------------------
extern "C" void kernel_launch(void* const* d_in, const int* in_sizes, int n_in,
                              void* d_out, int out_size, void* d_ws, size_t ws_size,
                              hipStream_t stream)
{
    const float* x  = (const float*)d_in[0];
    const float* Wq = (const float*)d_in[1];
    const float* bq = (const float*)d_in[2];
    const float* Wk = (const float*)d_in[3];
    const float* bk = (const float*)d_in[4];
    const float* Wv = (const float*)d_in[5];
    const float* bv = (const float*)d_in[6];
    float* out = (float*)d_out;

    float* qb = (float*)d_ws;
    float* kb = qb + QKV_ELEMS;
    float* vb = kb + QKV_ELEMS;

    dim3 g1(NB * NS / 64, NH);
    qkv_proj_kernel<<<g1, 256, 0, stream>>>(x, Wq, bq, Wk, bk, Wv, bv, qb, kb, vb);

    flash_kernel<<<NB * NH * 16, 256, 0, stream>>>(qb, kb, vb, out);
}

// Round 3
// 433.323 us; speedup vs baseline: 2.2608x; 2.2608x over previous
//
#include <hip/hip_runtime.h>
#include <math.h>

#define NB 16
#define NS 1024
#define ND 768
#define NH 12
#define NDH 64

static constexpr size_t QKV_ELEMS = (size_t)NB * NH * NS * NDH;  // 12.58M elems

typedef __attribute__((ext_vector_type(8))) short short8;   // 8 bf16 = 4 VGPRs
typedef __attribute__((ext_vector_type(4))) float f32x4;

__device__ __forceinline__ unsigned short bf16rtn(float x) {
    unsigned int b = __builtin_bit_cast(unsigned int, x);
    b += 0x7fffu + ((b >> 16) & 1u);
    return (unsigned short)(b >> 16);
}
__device__ __forceinline__ float bf16tof(unsigned short u) {
    return __builtin_bit_cast(float, (unsigned int)u << 16);
}

#define GLOAD_LDS16(g, l) __builtin_amdgcn_global_load_lds( \
    (const __attribute__((address_space(1))) unsigned int*)(g), \
    (__attribute__((address_space(3))) unsigned int*)(l), 16, 0, 0)

// ---------------------------------------------------------------------------
// Kernel 1: QKV projection -> bf16 hi/lo outputs in [B,H,S,64] layout.
//   q pre-scaled by 1/8. q,k emitted as hi+lo bf16 pairs (near-fp32 QK^T),
//   v as single bf16.
// ---------------------------------------------------------------------------
__global__ __launch_bounds__(256) void qkv_proj_kernel(
    const float* __restrict__ x,
    const float* __restrict__ Wq, const float* __restrict__ bq,
    const float* __restrict__ Wk, const float* __restrict__ bk,
    const float* __restrict__ Wv, const float* __restrict__ bv,
    unsigned short* __restrict__ qhw, unsigned short* __restrict__ qlw,
    unsigned short* __restrict__ khw, unsigned short* __restrict__ klw,
    unsigned short* __restrict__ vbw)
{
    __shared__ float xs[64][68];
    const int tb = blockIdx.x;
    const int h  = blockIdx.y;
    const int t  = threadIdx.x;
    const int e  = t & 63;
    const int tg = t >> 6;
    const long tok0 = (long)tb * 64;

    #pragma unroll
    for (int r = 0; r < 4; ++r) {
        const int vi  = r * 256 + t;
        const int row = vi >> 4;
        const int c4  = (vi & 15) << 2;
        const float4 val = *reinterpret_cast<const float4*>(
            &x[(tok0 + row) * ND + h * NDH + c4]);
        *reinterpret_cast<float4*>(&xs[row][c4]) = val;
    }
    __syncthreads();

    float acc[3][16];
    #pragma unroll
    for (int m = 0; m < 3; ++m)
        #pragma unroll
        for (int p = 0; p < 16; ++p) acc[m][p] = 0.f;

    #pragma unroll
    for (int dc = 0; dc < 4; ++dc) {
        float wr0[16], wr1[16], wr2[16];
        #pragma unroll
        for (int i4 = 0; i4 < 4; ++i4) {
            const size_t wbase = (size_t)(h * NDH + e) * NDH + dc * 16 + i4 * 4;
            const float4 a = *reinterpret_cast<const float4*>(&Wq[wbase]);
            const float4 b = *reinterpret_cast<const float4*>(&Wk[wbase]);
            const float4 c = *reinterpret_cast<const float4*>(&Wv[wbase]);
            wr0[i4*4+0]=a.x; wr0[i4*4+1]=a.y; wr0[i4*4+2]=a.z; wr0[i4*4+3]=a.w;
            wr1[i4*4+0]=b.x; wr1[i4*4+1]=b.y; wr1[i4*4+2]=b.z; wr1[i4*4+3]=b.w;
            wr2[i4*4+0]=c.x; wr2[i4*4+1]=c.y; wr2[i4*4+2]=c.z; wr2[i4*4+3]=c.w;
        }
        #pragma unroll
        for (int p = 0; p < 16; ++p) {
            const int token = p * 4 + tg;
            #pragma unroll
            for (int i = 0; i < 16; ++i) {
                const float xd = xs[token][dc * 16 + i];
                acc[0][p] = fmaf(xd, wr0[i], acc[0][p]);
                acc[1][p] = fmaf(xd, wr1[i], acc[1][p]);
                acc[2][p] = fmaf(xd, wr2[i], acc[2][p]);
            }
        }
    }

    const float bqv = bq[h * NDH + e];
    const float bkv = bk[h * NDH + e];
    const float bvv = bv[h * NDH + e];

    #pragma unroll
    for (int p = 0; p < 16; ++p) {
        const int gt = (int)tok0 + p * 4 + tg;
        const int b  = gt >> 10;
        const int s  = gt & 1023;
        const size_t oidx = ((size_t)(b * NH + h) * NS + s) * NDH + e;
        const float qv = (acc[0][p] + bqv) * 0.125f;
        const float kv = acc[1][p] + bkv;
        const float vv = acc[2][p] + bvv;
        const unsigned short qh_ = bf16rtn(qv);
        const unsigned short kh_ = bf16rtn(kv);
        qhw[oidx] = qh_;
        qlw[oidx] = bf16rtn(qv - bf16tof(qh_));
        khw[oidx] = kh_;
        klw[oidx] = bf16rtn(kv - bf16tof(kh_));
        vbw[oidx] = bf16rtn(vv);
    }
}

// ---------------------------------------------------------------------------
// Kernel 2: MFMA flash attention. Block = 256 thr = 4 waves. Q-block 128
// rows (32/wave), KV-tile 64. QK^T = hi/lo-split bf16 MFMA (near-fp32),
// PV = bf16 MFMA. K staged via global_load_lds with pre-swizzled source;
// V reg-stage-transposed; P via per-wave swizzled LDS (same-wave, no barrier).
// All ds_read_b128 patterns: 8 consecutive lanes -> 8 distinct 16B slots.
// ---------------------------------------------------------------------------
__global__ __launch_bounds__(256) void flash_mfma(
    const unsigned short* __restrict__ qh, const unsigned short* __restrict__ ql,
    const unsigned short* __restrict__ kh, const unsigned short* __restrict__ kl,
    const unsigned short* __restrict__ vb, float* __restrict__ out)
{
    __shared__ unsigned short Khi[64 * 64];   // [kv][d], 16B-slot XOR swizzle
    __shared__ unsigned short Klo[64 * 64];
    __shared__ unsigned short Vt [64 * 64];   // [d][kv], swizzled
    __shared__ unsigned short Pl [4][32 * 64];// per-wave [q][kv], swizzled

    const int bh = blockIdx.x;        // 0..191 ; XCD = bh % 8 (192 % 8 == 0)
    const int qt = blockIdx.y;        // 0..7
    const int t  = threadIdx.x;
    const int w  = t >> 6;
    const int l  = t & 63;
    const int l16 = l & 15;
    const int lg  = l >> 4;           // 0..3

    const size_t kvbase = (size_t)bh * NS * NDH;
    const int q0 = qt * 128 + w * 32;

    // ---- Q fragments (A-operand): lane holds Q[q0+m*16+l16][kc*32+lg*8 ..+7]
    short8 qfh[2][2], qfl[2][2];
    #pragma unroll
    for (int m = 0; m < 2; ++m)
        #pragma unroll
        for (int kc = 0; kc < 2; ++kc) {
            const size_t qidx = kvbase + (size_t)(q0 + m * 16 + l16) * NDH + kc * 32 + lg * 8;
            qfh[m][kc] = *reinterpret_cast<const short8*>(qh + qidx);
            qfl[m][kc] = *reinterpret_cast<const short8*>(ql + qidx);
        }

    // K staging assignment: waves 0,1 -> Khi rows 0-31/32-63; waves 2,3 -> Klo
    const unsigned short* ksrc = (w < 2) ? kh : kl;
    unsigned short* kdst = (w < 2) ? Khi : Klo;
    const int rowoff = (w & 1) * 32;
    const int lrow  = l >> 3;                 // 0..7 within 8-row chunk
    const int lslot = (l & 7) ^ lrow;         // pre-swizzled source slot

    // V staging: thread owns column kv=t&63, d-rows vdb..vdb+15
    const int vkv = t & 63;
    const int vdb = (t >> 6) * 16;

    f32x4 Oacc[2][4];
    float mi[2][4], li[2][4];
    #pragma unroll
    for (int m = 0; m < 2; ++m)
        #pragma unroll
        for (int r = 0; r < 4; ++r) {
            mi[m][r] = -INFINITY; li[m][r] = 0.f;
        }
    #pragma unroll
    for (int m = 0; m < 2; ++m)
        #pragma unroll
        for (int n = 0; n < 4; ++n)
            Oacc[m][n] = f32x4{0.f, 0.f, 0.f, 0.f};

    for (int kt = 0; kt < 16; ++kt) {
        // ---- stage K (4 x global_load_lds per wave, pre-swizzled source)
        #pragma unroll
        for (int i = 0; i < 4; ++i) {
            const int row = rowoff + i * 8 + lrow;
            const unsigned short* g = ksrc + kvbase + (size_t)(kt * 64 + row) * NDH + lslot * 8;
            GLOAD_LDS16(g, kdst + (rowoff + i * 8) * 64);
        }
        // ---- stage V transposed (reg path)
        {
            const size_t vsrc = kvbase + (size_t)(kt * 64 + vkv) * NDH + vdb;
            const short8 v0 = *reinterpret_cast<const short8*>(vb + vsrc);
            const short8 v1 = *reinterpret_cast<const short8*>(vb + vsrc + 8);
            #pragma unroll
            for (int j = 0; j < 8; ++j) {
                const int d0 = vdb + j, d1 = vdb + 8 + j;
                Vt[d0 * 64 + (vkv ^ ((d0 & 7) << 3))] = (unsigned short)v0[j];
                Vt[d1 * 64 + (vkv ^ ((d1 & 7) << 3))] = (unsigned short)v1[j];
            }
        }
        __syncthreads();

        // ---- QK^T: S[m][n] (q rows x kv cols), hi/lo split
        f32x4 S[2][4];
        #pragma unroll
        for (int m = 0; m < 2; ++m)
            #pragma unroll
            for (int n = 0; n < 4; ++n) S[m][n] = f32x4{0.f, 0.f, 0.f, 0.f};

        #pragma unroll
        for (int n = 0; n < 4; ++n) {
            const int kvr = n * 16 + l16;
            const int sw  = (kvr & 7) << 3;
            #pragma unroll
            for (int kc = 0; kc < 2; ++kc) {
                const int dd = kc * 32 + lg * 8;
                const short8 bh_ = *reinterpret_cast<const short8*>(&Khi[kvr * 64 + (dd ^ sw)]);
                const short8 bl_ = *reinterpret_cast<const short8*>(&Klo[kvr * 64 + (dd ^ sw)]);
                #pragma unroll
                for (int m = 0; m < 2; ++m) {
                    S[m][n] = __builtin_amdgcn_mfma_f32_16x16x32_bf16(qfh[m][kc], bh_, S[m][n], 0, 0, 0);
                    S[m][n] = __builtin_amdgcn_mfma_f32_16x16x32_bf16(qfl[m][kc], bh_, S[m][n], 0, 0, 0);
                    S[m][n] = __builtin_amdgcn_mfma_f32_16x16x32_bf16(qfh[m][kc], bl_, S[m][n], 0, 0, 0);
                }
            }
        }

        // ---- online softmax (row = q = lg*4+r within m-chunk; cols spread
        //      over n (in-reg) and l16 lanes -> shfl_xor 1,2,4,8)
        #pragma unroll
        for (int m = 0; m < 2; ++m)
            #pragma unroll
            for (int r = 0; r < 4; ++r) {
                float rm = fmaxf(fmaxf(S[m][0][r], S[m][1][r]), fmaxf(S[m][2][r], S[m][3][r]));
                rm = fmaxf(rm, __shfl_xor(rm, 1));
                rm = fmaxf(rm, __shfl_xor(rm, 2));
                rm = fmaxf(rm, __shfl_xor(rm, 4));
                rm = fmaxf(rm, __shfl_xor(rm, 8));
                const float mn_ = fmaxf(mi[m][r], rm);
                const float c   = __expf(mi[m][r] - mn_);
                mi[m][r] = mn_;
                float rs = 0.f;
                #pragma unroll
                for (int n = 0; n < 4; ++n) {
                    const float p = __expf(S[m][n][r] - mn_);
                    S[m][n][r] = p;
                    rs += p;
                }
                rs += __shfl_xor(rs, 1);
                rs += __shfl_xor(rs, 2);
                rs += __shfl_xor(rs, 4);
                rs += __shfl_xor(rs, 8);
                li[m][r] = li[m][r] * c + rs;
                #pragma unroll
                for (int n = 0; n < 4; ++n) Oacc[m][n][r] *= c;
            }

        // ---- P -> per-wave swizzled LDS (bf16); same-wave producer/consumer
        unsigned short* P = Pl[w];
        #pragma unroll
        for (int m = 0; m < 2; ++m)
            #pragma unroll
            for (int r = 0; r < 4; ++r) {
                const int q = m * 16 + lg * 4 + r;
                const int sw = (q & 7) << 3;
                #pragma unroll
                for (int n = 0; n < 4; ++n)
                    P[q * 64 + ((n * 16 + l16) ^ sw)] = bf16rtn(S[m][n][r]);
            }

        // ---- P A-fragments
        short8 pf[2][2];
        #pragma unroll
        for (int m = 0; m < 2; ++m)
            #pragma unroll
            for (int kc = 0; kc < 2; ++kc) {
                const int q = m * 16 + l16;
                pf[m][kc] = *reinterpret_cast<const short8*>(
                    &P[q * 64 + ((kc * 32 + lg * 8) ^ ((q & 7) << 3))]);
            }

        // ---- PV accumulate
        #pragma unroll
        for (int n = 0; n < 4; ++n) {
            const int d  = n * 16 + l16;
            const int sw = (d & 7) << 3;
            #pragma unroll
            for (int kc = 0; kc < 2; ++kc) {
                const short8 vf = *reinterpret_cast<const short8*>(
                    &Vt[d * 64 + ((kc * 32 + lg * 8) ^ sw)]);
                #pragma unroll
                for (int m = 0; m < 2; ++m)
                    Oacc[m][n] = __builtin_amdgcn_mfma_f32_16x16x32_bf16(pf[m][kc], vf, Oacc[m][n], 0, 0, 0);
            }
        }
        __syncthreads();
    }

    // ---- epilogue: out[b, s, h*64 + d]
    const int b = bh / NH;
    const int h = bh % NH;
    #pragma unroll
    for (int m = 0; m < 2; ++m)
        #pragma unroll
        for (int r = 0; r < 4; ++r) {
            const float inv = 1.0f / li[m][r];
            const int q = q0 + m * 16 + lg * 4 + r;
            #pragma unroll
            for (int n = 0; n < 4; ++n)
                out[((size_t)b * NS + q) * ND + h * NDH + n * 16 + l16] = Oacc[m][n][r] * inv;
        }
}

// ---------------------------------------------------------------------------
extern "C" void kernel_launch(void* const* d_in, const int* in_sizes, int n_in,
                              void* d_out, int out_size, void* d_ws, size_t ws_size,
                              hipStream_t stream)
{
    const float* x  = (const float*)d_in[0];
    const float* Wq = (const float*)d_in[1];
    const float* bq = (const float*)d_in[2];
    const float* Wk = (const float*)d_in[3];
    const float* bk = (const float*)d_in[4];
    const float* Wv = (const float*)d_in[5];
    const float* bv = (const float*)d_in[6];
    float* out = (float*)d_out;

    unsigned short* qhw = (unsigned short*)d_ws;
    unsigned short* qlw = qhw + QKV_ELEMS;
    unsigned short* khw = qlw + QKV_ELEMS;
    unsigned short* klw = khw + QKV_ELEMS;
    unsigned short* vbw = klw + QKV_ELEMS;

    dim3 g1(NB * NS / 64, NH);
    qkv_proj_kernel<<<g1, 256, 0, stream>>>(x, Wq, bq, Wk, bk, Wv, bv,
                                            qhw, qlw, khw, klw, vbw);

    dim3 g2(NB * NH, 8);   // x = bh (fixes XCD per head), y = q-tile
    flash_mfma<<<g2, 256, 0, stream>>>(qhw, qlw, khw, klw, vbw, out);
}

// Round 4
// 325.206 us; speedup vs baseline: 3.0124x; 1.3325x over previous
//
#include <hip/hip_runtime.h>
#include <math.h>

#define NB 16
#define NS 1024
#define ND 768
#define NH 12
#define NDH 64

static constexpr size_t QKV_ELEMS = (size_t)NB * NH * NS * NDH;  // 12.58M elems
static constexpr float QSCALE = 0.125f * 1.44269504088896f;      // 1/sqrt(64) * log2(e)

typedef __attribute__((ext_vector_type(8))) _Float16 half8;   // MFMA A/B frag
typedef __attribute__((ext_vector_type(2))) _Float16 half2t;
typedef __attribute__((ext_vector_type(4))) float f32x4;      // MFMA C/D frag

// ---------------------------------------------------------------------------
// Kernel 1: QKV projection via fp16 MFMA (x split hi/lo for near-fp32 accuracy).
//   x: [B*S, 768] fp32. W*: [H, 64, 64] (out,in). b*: [H, 64].
//   Outputs: q,k fp16 [bh, s, d] (q pre-scaled by 0.125*log2e), vT fp16 [bh, d, s].
// grid (128 token-tiles, 12 heads), block 256 = 4 waves x 32 tokens.
// ---------------------------------------------------------------------------
__device__ __forceinline__ void proj_one(
    const float* __restrict__ W, int h, int l16, int lg,
    const half8 xh[2][2], const half8 xl[2][2], f32x4 acc[2][4])
{
    #pragma unroll
    for (int n = 0; n < 4; ++n)
        #pragma unroll
        for (int kc = 0; kc < 2; ++kc) {
            const float* pw = W + (size_t)(h * NDH + n * 16 + l16) * NDH + kc * 32 + lg * 8;
            const float4 a = *reinterpret_cast<const float4*>(pw);
            const float4 b = *reinterpret_cast<const float4*>(pw + 4);
            const float wv[8] = {a.x, a.y, a.z, a.w, b.x, b.y, b.z, b.w};
            half8 wf;
            #pragma unroll
            for (int j = 0; j < 8; ++j) wf[j] = (_Float16)wv[j];
            #pragma unroll
            for (int m = 0; m < 2; ++m) {
                acc[m][n] = __builtin_amdgcn_mfma_f32_16x16x32_f16(xh[m][kc], wf, acc[m][n], 0, 0, 0);
                acc[m][n] = __builtin_amdgcn_mfma_f32_16x16x32_f16(xl[m][kc], wf, acc[m][n], 0, 0, 0);
            }
        }
}

__global__ __launch_bounds__(256) void qkv_mfma(
    const float* __restrict__ x,
    const float* __restrict__ Wq, const float* __restrict__ bq,
    const float* __restrict__ Wk, const float* __restrict__ bk,
    const float* __restrict__ Wv, const float* __restrict__ bv,
    _Float16* __restrict__ qo, _Float16* __restrict__ ko, _Float16* __restrict__ vT)
{
    const int tb = blockIdx.x;            // 0..127
    const int h  = blockIdx.y;            // 0..11
    const int t  = threadIdx.x;
    const int w  = t >> 6;
    const int l  = t & 63;
    const int l16 = l & 15, lg = l >> 4;
    const int tok0 = tb * 128 + w * 32;   // wave's 32 tokens (same batch: 1024%128==0)
    const int b  = tok0 >> 10;
    const int s0 = tok0 & 1023;
    const int bh = b * NH + h;

    // A-frags: x hi/lo fp16. lane: row=l16 (token), k=lg*8+j (d)
    half8 xh[2][2], xl[2][2];
    #pragma unroll
    for (int m = 0; m < 2; ++m)
        #pragma unroll
        for (int kc = 0; kc < 2; ++kc) {
            const float* px = x + (size_t)(tok0 + m * 16 + l16) * ND + h * NDH + kc * 32 + lg * 8;
            const float4 a = *reinterpret_cast<const float4*>(px);
            const float4 c = *reinterpret_cast<const float4*>(px + 4);
            const float vv[8] = {a.x, a.y, a.z, a.w, c.x, c.y, c.z, c.w};
            #pragma unroll
            for (int j = 0; j < 8; ++j) {
                const _Float16 hi = (_Float16)vv[j];
                xh[m][kc][j] = hi;
                xl[m][kc][j] = (_Float16)(vv[j] - (float)hi);
            }
        }

    f32x4 acc[2][4];

    // ---- Q
    #pragma unroll
    for (int m = 0; m < 2; ++m)
        #pragma unroll
        for (int n = 0; n < 4; ++n) acc[m][n] = f32x4{0.f, 0.f, 0.f, 0.f};
    proj_one(Wq, h, l16, lg, xh, xl, acc);
    #pragma unroll
    for (int n = 0; n < 4; ++n) {
        const float bb = bq[h * NDH + n * 16 + l16];
        #pragma unroll
        for (int m = 0; m < 2; ++m)
            #pragma unroll
            for (int r = 0; r < 4; ++r)
                qo[((size_t)bh * NS + s0 + m * 16 + lg * 4 + r) * NDH + n * 16 + l16] =
                    (_Float16)((acc[m][n][r] + bb) * QSCALE);
    }

    // ---- K
    #pragma unroll
    for (int m = 0; m < 2; ++m)
        #pragma unroll
        for (int n = 0; n < 4; ++n) acc[m][n] = f32x4{0.f, 0.f, 0.f, 0.f};
    proj_one(Wk, h, l16, lg, xh, xl, acc);
    #pragma unroll
    for (int n = 0; n < 4; ++n) {
        const float bb = bk[h * NDH + n * 16 + l16];
        #pragma unroll
        for (int m = 0; m < 2; ++m)
            #pragma unroll
            for (int r = 0; r < 4; ++r)
                ko[((size_t)bh * NS + s0 + m * 16 + lg * 4 + r) * NDH + n * 16 + l16] =
                    (_Float16)(acc[m][n][r] + bb);
    }

    // ---- V (transposed write: vT[bh][d][s]; L2 merges the 2B scatters)
    #pragma unroll
    for (int m = 0; m < 2; ++m)
        #pragma unroll
        for (int n = 0; n < 4; ++n) acc[m][n] = f32x4{0.f, 0.f, 0.f, 0.f};
    proj_one(Wv, h, l16, lg, xh, xl, acc);
    #pragma unroll
    for (int n = 0; n < 4; ++n) {
        const float bb = bv[h * NDH + n * 16 + l16];
        #pragma unroll
        for (int m = 0; m < 2; ++m)
            #pragma unroll
            for (int r = 0; r < 4; ++r)
                vT[((size_t)bh * NDH + n * 16 + l16) * NS + s0 + m * 16 + lg * 4 + r] =
                    (_Float16)(acc[m][n][r] + bb);
    }
}

// ---------------------------------------------------------------------------
// Kernel 2: barrier-free MFMA flash attention. Block = 1 wave (64 thr),
// 32 q-rows per block, KV-tile 64, 16 iterations. K/Q/V fragments loaded
// DIRECTLY from global (L1/L2-hot; 16B contiguous per lane). Swapped QK^T
// (S^T = K*Q^T) makes softmax mostly in-lane (2 shfl per stat). P crosses
// lanes through a row-XOR-swizzled LDS tile (same-wave, no barrier).
// ---------------------------------------------------------------------------
__global__ __launch_bounds__(64) void flash_mfma(
    const _Float16* __restrict__ q, const _Float16* __restrict__ k,
    const _Float16* __restrict__ vT, float* __restrict__ out)
{
    __shared__ __align__(16) _Float16 PT[32 * 64];  // [q 0..31][kv 0..63], 16B-slot row-XOR swizzle

    const int i   = blockIdx.x;           // 6144 blocks
    const int xcd = i & 7;
    const int c   = i >> 3;
    const int bh  = xcd * 24 + (c >> 5);  // one head per XCD chunk -> K/V/Q L2-hot
    const int q0  = (c & 31) * 32;
    const int l   = threadIdx.x;
    const int l16 = l & 15, lg = l >> 4;

    const size_t qkbase = (size_t)bh * NS * NDH;
    const size_t vtbase = (size_t)bh * NDH * NS;

    // Q B-frags (loop-invariant): lane: col=l16 (q), k=lg*8+j (d)
    half8 qf[2][2];
    #pragma unroll
    for (int n2 = 0; n2 < 2; ++n2)
        #pragma unroll
        for (int kc = 0; kc < 2; ++kc)
            qf[n2][kc] = *reinterpret_cast<const half8*>(
                q + qkbase + (size_t)(q0 + n2 * 16 + l16) * NDH + kc * 32 + lg * 8);

    f32x4 Oacc[2][4];
    #pragma unroll
    for (int m = 0; m < 2; ++m)
        #pragma unroll
        for (int n = 0; n < 4; ++n) Oacc[m][n] = f32x4{0.f, 0.f, 0.f, 0.f};
    float mi[2] = {-INFINITY, -INFINITY};
    float li[2] = {0.f, 0.f};

    // K A-frag prefetch for kt=0: lane: row=l16 (kv), k=lg*8+j (d)
    half8 kf[4][2];
    #pragma unroll
    for (int m4 = 0; m4 < 4; ++m4)
        #pragma unroll
        for (int kc = 0; kc < 2; ++kc)
            kf[m4][kc] = *reinterpret_cast<const half8*>(
                k + qkbase + (size_t)(m4 * 16 + l16) * NDH + kc * 32 + lg * 8);

    for (int kt = 0; kt < 16; ++kt) {
        const int kvb = kt * 64;

        // ---- issue V B-frags early (used after softmax): lane: col=l16 (d), k=lg*8+j (kv)
        half8 vf[4][2];
        #pragma unroll
        for (int n4 = 0; n4 < 4; ++n4)
            #pragma unroll
            for (int kc = 0; kc < 2; ++kc)
                vf[n4][kc] = *reinterpret_cast<const half8*>(
                    vT + vtbase + (size_t)(n4 * 16 + l16) * NS + kvb + kc * 32 + lg * 8);

        // ---- S^T = K * Q^T : st[m4][n2], element r -> kv = m4*16+lg*4+r, q = n2*16+l16
        f32x4 st[4][2];
        #pragma unroll
        for (int m4 = 0; m4 < 4; ++m4)
            #pragma unroll
            for (int n2 = 0; n2 < 2; ++n2) {
                st[m4][n2] = f32x4{0.f, 0.f, 0.f, 0.f};
                #pragma unroll
                for (int kc = 0; kc < 2; ++kc)
                    st[m4][n2] = __builtin_amdgcn_mfma_f32_16x16x32_f16(
                        kf[m4][kc], qf[n2][kc], st[m4][n2], 0, 0, 0);
            }

        // ---- prefetch K for kt+1 (latency covered by softmax+PV)
        half8 kf2[4][2];
        if (kt < 15) {
            #pragma unroll
            for (int m4 = 0; m4 < 4; ++m4)
                #pragma unroll
                for (int kc = 0; kc < 2; ++kc)
                    kf2[m4][kc] = *reinterpret_cast<const half8*>(
                        k + qkbase + (size_t)(kvb + 64 + m4 * 16 + l16) * NDH + kc * 32 + lg * 8);
        }

        // ---- online softmax in exp2 domain (scale folded into q)
        float cfac[2];
        #pragma unroll
        for (int n2 = 0; n2 < 2; ++n2) {
            float pm = st[0][n2][0];
            #pragma unroll
            for (int m4 = 0; m4 < 4; ++m4)
                #pragma unroll
                for (int r = 0; r < 4; ++r) pm = fmaxf(pm, st[m4][n2][r]);
            pm = fmaxf(pm, __shfl_xor(pm, 16));
            pm = fmaxf(pm, __shfl_xor(pm, 32));
            const float mn = fmaxf(mi[n2], pm);
            cfac[n2] = __builtin_amdgcn_exp2f(mi[n2] - mn);   // first iter: exp2(-inf)=0
            mi[n2] = mn;
            float rs = 0.f;
            #pragma unroll
            for (int m4 = 0; m4 < 4; ++m4)
                #pragma unroll
                for (int r = 0; r < 4; ++r) {
                    const float p = __builtin_amdgcn_exp2f(st[m4][n2][r] - mn);
                    st[m4][n2][r] = p;
                    rs += p;
                }
            rs += __shfl_xor(rs, 16);
            rs += __shfl_xor(rs, 32);
            li[n2] = li[n2] * cfac[n2] + rs;
        }

        // ---- rescale Oacc BEFORE adding this tile's PV
        #pragma unroll
        for (int m2 = 0; m2 < 2; ++m2) {
            float cb[4];
            #pragma unroll
            for (int r = 0; r < 4; ++r) cb[r] = __shfl(cfac[m2], lg * 4 + r);
            #pragma unroll
            for (int n4 = 0; n4 < 4; ++n4)
                #pragma unroll
                for (int r = 0; r < 4; ++r) Oacc[m2][n4][r] *= cb[r];
        }

        // ---- P -> PT (packed fp16, b64 writes, 16B-slot XOR swizzle), same-wave
        #pragma unroll
        for (int n2 = 0; n2 < 2; ++n2) {
            const int row = n2 * 16 + l16;
            #pragma unroll
            for (int m4 = 0; m4 < 4; ++m4) {
                const unsigned int p01 = __builtin_bit_cast(unsigned int,
                    __builtin_amdgcn_cvt_pkrtz(st[m4][n2][0], st[m4][n2][1]));
                const unsigned int p23 = __builtin_bit_cast(unsigned int,
                    __builtin_amdgcn_cvt_pkrtz(st[m4][n2][2], st[m4][n2][3]));
                const int swz = (m4 * 2 + (lg >> 1)) ^ (row & 7);   // 16B slot index
                uint2* dst = reinterpret_cast<uint2*>(&PT[row * 64 + swz * 8 + (lg & 1) * 4]);
                *dst = uint2{p01, p23};
            }
        }

        // ---- P A-frags: row = m2*16+l16 (q), k = kv = kc*32+lg*8+j
        half8 pf[2][2];
        #pragma unroll
        for (int m2 = 0; m2 < 2; ++m2) {
            const int row = m2 * 16 + l16;
            #pragma unroll
            for (int kc = 0; kc < 2; ++kc) {
                const int swz = (kc * 4 + lg) ^ (row & 7);
                pf[m2][kc] = *reinterpret_cast<const half8*>(&PT[row * 64 + swz * 8]);
            }
        }

        // ---- PV accumulate
        #pragma unroll
        for (int m2 = 0; m2 < 2; ++m2)
            #pragma unroll
            for (int n4 = 0; n4 < 4; ++n4)
                #pragma unroll
                for (int kc = 0; kc < 2; ++kc)
                    Oacc[m2][n4] = __builtin_amdgcn_mfma_f32_16x16x32_f16(
                        pf[m2][kc], vf[n4][kc], Oacc[m2][n4], 0, 0, 0);

        // rotate prefetched K
        #pragma unroll
        for (int m4 = 0; m4 < 4; ++m4)
            #pragma unroll
            for (int kc = 0; kc < 2; ++kc) kf[m4][kc] = kf2[m4][kc];
    }

    // ---- epilogue
    const int b = bh / NH;
    const int h = bh % NH;
    float inv[2] = {1.f / li[0], 1.f / li[1]};
    #pragma unroll
    for (int m2 = 0; m2 < 2; ++m2)
        #pragma unroll
        for (int r = 0; r < 4; ++r) {
            const float ib = __shfl(inv[m2], lg * 4 + r);
            const int s = q0 + m2 * 16 + lg * 4 + r;
            #pragma unroll
            for (int n4 = 0; n4 < 4; ++n4)
                out[((size_t)b * NS + s) * ND + h * NDH + n4 * 16 + l16] = Oacc[m2][n4][r] * ib;
        }
}

// ---------------------------------------------------------------------------
extern "C" void kernel_launch(void* const* d_in, const int* in_sizes, int n_in,
                              void* d_out, int out_size, void* d_ws, size_t ws_size,
                              hipStream_t stream)
{
    const float* x  = (const float*)d_in[0];
    const float* Wq = (const float*)d_in[1];
    const float* bq = (const float*)d_in[2];
    const float* Wk = (const float*)d_in[3];
    const float* bk = (const float*)d_in[4];
    const float* Wv = (const float*)d_in[5];
    const float* bv = (const float*)d_in[6];
    float* out = (float*)d_out;

    _Float16* qb = (_Float16*)d_ws;
    _Float16* kb = qb + QKV_ELEMS;
    _Float16* vt = kb + QKV_ELEMS;

    dim3 g1(NB * NS / 128, NH);
    qkv_mfma<<<g1, 256, 0, stream>>>(x, Wq, bq, Wk, bk, Wv, bv, qb, kb, vt);

    flash_mfma<<<NB * NH * 32, 64, 0, stream>>>(qb, kb, vt, out);
}